// Round 13
// baseline (15912.917 us; speedup 1.0000x reference)
//
#include <hip/hip_runtime.h>

#define TT 256
#define BB 32
#define HH 1024
#define GG 4096

typedef __attribute__((ext_vector_type(8))) short short8;
typedef __attribute__((ext_vector_type(4))) float f32x4;

__device__ __forceinline__ unsigned short rne_bf16(float x) {
    unsigned u = __float_as_uint(x);
    unsigned r = (u + 0x7FFFu + ((u >> 16) & 1u)) >> 16;
    return (unsigned short)r;
}
__device__ __forceinline__ float bf16f(unsigned short s) {
    return __uint_as_float((unsigned)s << 16);
}

// ---------- transpose x[B,T,H] -> seq bf16x3 splits ----------
__global__ __launch_bounds__(256) void k_transpose3(const float* __restrict__ x,
                                                    unsigned short* __restrict__ s1,
                                                    unsigned short* __restrict__ s2,
                                                    unsigned short* __restrict__ s3) {
    int idx = blockIdx.x * 256 + threadIdx.x;
    int k4 = idx & 255;
    int tb = idx >> 8;
    int t = tb >> 5, b = tb & 31;
    float4 v = ((const float4*)x)[((size_t)b * TT + t) * 256 + k4];
    float xs[4] = {v.x, v.y, v.z, v.w};
    ushort4 o1, o2, o3;
    unsigned short* p1 = (unsigned short*)&o1;
    unsigned short* p2 = (unsigned short*)&o2;
    unsigned short* p3 = (unsigned short*)&o3;
#pragma unroll
    for (int e = 0; e < 4; ++e) {
        unsigned short q1 = rne_bf16(xs[e]);
        float r1 = xs[e] - bf16f(q1);
        unsigned short q2 = rne_bf16(r1);
        float r2 = r1 - bf16f(q2);
        p1[e] = q1; p2[e] = q2; p3[e] = rne_bf16(r2);
    }
    size_t off = (size_t)tb * HH + k4 * 4;
    *(ushort4*)&s1[off] = o1;
    *(ushort4*)&s2[off] = o2;
    *(ushort4*)&s3[off] = o3;
}

// ---------- transpose x[B,T,H] -> seq[T,B,H] fp32 (fallback) ----------
__global__ __launch_bounds__(256) void k_transpose(const float* __restrict__ x, float* __restrict__ seq) {
    int idx = blockIdx.x * 256 + threadIdx.x;
    int k4 = idx & 255;
    int tb = idx >> 8;
    int t = tb >> 5, b = tb & 31;
    float4 v = ((const float4*)x)[((size_t)b * TT + t) * 256 + k4];
    ((float4*)seq)[(size_t)tb * 256 + k4] = v;
}

__global__ __launch_bounds__(256) void k_init_hc(const float* __restrict__ h0, const float* __restrict__ c0,
                                                 float* __restrict__ h, float* __restrict__ c) {
    int i = blockIdx.x * 256 + threadIdx.x;
    ((float4*)h)[i] = ((const float4*)h0)[i];
    ((float4*)c)[i] = ((const float4*)c0)[i];
}

__global__ __launch_bounds__(256) void k_init_hc2(const float* __restrict__ h0, const float* __restrict__ c0,
                                                  float* __restrict__ h, float* __restrict__ c,
                                                  unsigned short* __restrict__ hb1,
                                                  unsigned short* __restrict__ hb2,
                                                  unsigned short* __restrict__ hb3) {
    int i = blockIdx.x * 256 + threadIdx.x;
    float4 hv = ((const float4*)h0)[i];
    ((float4*)h)[i] = hv;
    ((float4*)c)[i] = ((const float4*)c0)[i];
    float xs[4] = {hv.x, hv.y, hv.z, hv.w};
    ushort4 o1, o2, o3;
    unsigned short* p1 = (unsigned short*)&o1;
    unsigned short* p2 = (unsigned short*)&o2;
    unsigned short* p3 = (unsigned short*)&o3;
#pragma unroll
    for (int e = 0; e < 4; ++e) {
        unsigned short s1 = rne_bf16(xs[e]);
        float r1 = xs[e] - bf16f(s1);
        unsigned short s2 = rne_bf16(r1);
        float r2 = r1 - bf16f(s2);
        p1[e] = s1; p2[e] = s2; p3[e] = rne_bf16(r2);
    }
    *(ushort4*)&hb1[i * 4] = o1;
    *(ushort4*)&hb2[i * 4] = o2;
    *(ushort4*)&hb3[i * 4] = o3;
}

__global__ __launch_bounds__(256) void k_copy_hc(const float* __restrict__ h, const float* __restrict__ c,
                                                 float* __restrict__ oh, float* __restrict__ oc) {
    int i = blockIdx.x * 256 + threadIdx.x;
    ((float4*)oh)[i] = ((const float4*)h)[i];
    ((float4*)oc)[i] = ((const float4*)c)[i];
}

// ---------- Wr[1024,4096] -> WrT[4096,1024] fp32 (fallback scan path) ----------
__global__ __launch_bounds__(256) void k_wrt(const float* __restrict__ Wr, float* __restrict__ WrT) {
    __shared__ float tile[64][65];
    int c0 = blockIdx.x * 64;
    int k0 = blockIdx.y * 64;
    int tid = threadIdx.x;
    int tr = tid >> 4, tc4 = tid & 15;
#pragma unroll
    for (int p = 0; p < 4; ++p) {
        int r = p * 16 + tr;
        float4 v = *(const float4*)&Wr[(size_t)(k0 + r) * GG + c0 + tc4 * 4];
        tile[r][tc4 * 4 + 0] = v.x;
        tile[r][tc4 * 4 + 1] = v.y;
        tile[r][tc4 * 4 + 2] = v.z;
        tile[r][tc4 * 4 + 3] = v.w;
    }
    __syncthreads();
#pragma unroll
    for (int p = 0; p < 4; ++p) {
        int cc = p * 16 + tr;
        float4 v;
        v.x = tile[tc4 * 4 + 0][cc];
        v.y = tile[tc4 * 4 + 1][cc];
        v.z = tile[tc4 * 4 + 2][cc];
        v.w = tile[tc4 * 4 + 3][cc];
        *(float4*)&WrT[(size_t)(c0 + cc) * 1024 + k0 + tc4 * 4] = v;
    }
}

// ---------- Wr -> gate-permuted bf16x3 wrb[blk16][16(g*4+d)][1024 k] (proven R11) ----------
__global__ __launch_bounds__(256) void k_wrt3(const float* __restrict__ Wr, unsigned short* __restrict__ W1,
                                              unsigned short* __restrict__ W2, unsigned short* __restrict__ W3) {
    __shared__ float tile[64][65];
    int c0 = blockIdx.x * 64;
    int k0 = blockIdx.y * 64;
    int tid = threadIdx.x;
    int tr = tid >> 4, tc4 = tid & 15;
#pragma unroll
    for (int p = 0; p < 4; ++p) {
        int r = p * 16 + tr;
        float4 v = *(const float4*)&Wr[(size_t)(k0 + r) * GG + c0 + tc4 * 4];
        tile[r][tc4 * 4 + 0] = v.x;
        tile[r][tc4 * 4 + 1] = v.y;
        tile[r][tc4 * 4 + 2] = v.z;
        tile[r][tc4 * 4 + 3] = v.w;
    }
    __syncthreads();
    int cc = tid & 63, kq = tid >> 6;
    int G = c0 + cc;
    int outrow = ((G & 1023) >> 2) * 16 + (G >> 10) * 4 + (G & 3);
    size_t obase = (size_t)outrow * 1024 + k0 + kq * 16;
    unsigned short t1[16], t2[16], t3[16];
#pragma unroll
    for (int e = 0; e < 16; ++e) {
        float v = tile[kq * 16 + e][cc];
        unsigned short s1 = rne_bf16(v);
        float r1 = v - bf16f(s1);
        unsigned short s2 = rne_bf16(r1);
        float r2 = r1 - bf16f(s2);
        t1[e] = s1; t2[e] = s2; t3[e] = rne_bf16(r2);
    }
#pragma unroll
    for (int hlf = 0; hlf < 2; ++hlf) {
        *(short8*)&W1[obase + hlf * 8] = *(short8*)&t1[hlf * 8];
        *(short8*)&W2[obase + hlf * 8] = *(short8*)&t2[hlf * 8];
        *(short8*)&W3[obase + hlf * 8] = *(short8*)&t3[hlf * 8];
    }
}

// ---------- W[1024,N] -> 3x bf16-split WT[N][1024] ----------
__global__ __launch_bounds__(256) void k_wt3(const float* __restrict__ W, int N,
                                             unsigned short* __restrict__ W1,
                                             unsigned short* __restrict__ W2,
                                             unsigned short* __restrict__ W3) {
    __shared__ float tile[64][65];
    int c0 = blockIdx.x * 64;
    int k0 = blockIdx.y * 64;
    int tid = threadIdx.x;
    int tr = tid >> 4, tc4 = tid & 15;
#pragma unroll
    for (int p = 0; p < 4; ++p) {
        int r = p * 16 + tr;
        float4 v = *(const float4*)&W[(size_t)(k0 + r) * N + c0 + tc4 * 4];
        tile[r][tc4 * 4 + 0] = v.x;
        tile[r][tc4 * 4 + 1] = v.y;
        tile[r][tc4 * 4 + 2] = v.z;
        tile[r][tc4 * 4 + 3] = v.w;
    }
    __syncthreads();
#pragma unroll
    for (int p = 0; p < 4; ++p) {
        int cc = p * 16 + tr;
        ushort4 o1, o2, o3;
        unsigned short* po1 = (unsigned short*)&o1;
        unsigned short* po2 = (unsigned short*)&o2;
        unsigned short* po3 = (unsigned short*)&o3;
#pragma unroll
        for (int e = 0; e < 4; ++e) {
            float v = tile[tc4 * 4 + e][cc];
            unsigned short s1 = rne_bf16(v);
            float r1 = v - bf16f(s1);
            unsigned short s2 = rne_bf16(r1);
            float r2 = r1 - bf16f(s2);
            po1[e] = s1; po2[e] = s2; po3[e] = rne_bf16(r2);
        }
        size_t off = (size_t)(c0 + cc) * 1024 + k0 + tc4 * 4;
        *(ushort4*)&W1[off] = o1;
        *(ushort4*)&W2[off] = o2;
        *(ushort4*)&W3[off] = o3;
    }
}

// ---------- MFMA bf16x3 GEMM, pre-split A/B, software-pipelined staging (T14) ----------
// MODE 0: C[m][4096] row-major (xw). MODE 1: m=t*32+b scattered to C[b][t][1024] (head).
template <int MODE>
__global__ __launch_bounds__(256, 2) void k_gemm_mx3s(const unsigned short* __restrict__ A1,
                                                      const unsigned short* __restrict__ A2,
                                                      const unsigned short* __restrict__ A3,
                                                      const unsigned short* __restrict__ B1,
                                                      const unsigned short* __restrict__ B2,
                                                      const unsigned short* __restrict__ B3,
                                                      const float* __restrict__ bias, float* __restrict__ C) {
    __shared__ unsigned short Asl[3][6144];   // [128 m][48 k-pad]
    __shared__ unsigned short Bsl[3][6144];   // [128 n][48 k-pad]
    int tid = threadIdx.x;
    int m0 = blockIdx.x * 128, n0 = blockIdx.y * 128;
    int lane = tid & 63, wv = tid >> 6;
    int wr = (wv >> 1) * 64, wc = (wv & 1) * 64;
    int l15 = lane & 15, ko = (lane >> 4) * 8;

    f32x4 acc[4][4];
#pragma unroll
    for (int i = 0; i < 4; ++i)
#pragma unroll
        for (int j = 0; j < 4; ++j) acc[i][j] = (f32x4){0.f, 0.f, 0.f, 0.f};

    const unsigned short* Ag[3] = {A1, A2, A3};
    const unsigned short* Bg[3] = {B1, B2, B3};
    int srow = tid >> 2, skq = tid & 3;       // staging role: rows srow, srow+64

    // prefetch k0 = 0 tiles into registers
    short8 ra[3][2], rbv[3][2];
#pragma unroll
    for (int sp = 0; sp < 3; ++sp)
#pragma unroll
        for (int i = 0; i < 2; ++i) {
            int r = srow + i * 64;
            ra[sp][i]  = *(const short8*)&Ag[sp][(size_t)(m0 + r) * 1024 + skq * 8];
            rbv[sp][i] = *(const short8*)&Bg[sp][(size_t)(n0 + r) * 1024 + skq * 8];
        }

    for (int k0 = 0; k0 < 1024; k0 += 32) {
        // write current regs -> LDS
#pragma unroll
        for (int sp = 0; sp < 3; ++sp)
#pragma unroll
            for (int i = 0; i < 2; ++i) {
                int r = srow + i * 64;
                *(short8*)&Asl[sp][r * 48 + skq * 8] = ra[sp][i];
                *(short8*)&Bsl[sp][r * 48 + skq * 8] = rbv[sp][i];
            }
        __syncthreads();
        // issue next tile's loads (overlap with MFMA below)
        if (k0 + 32 < 1024) {
#pragma unroll
            for (int sp = 0; sp < 3; ++sp)
#pragma unroll
                for (int i = 0; i < 2; ++i) {
                    int r = srow + i * 64;
                    ra[sp][i]  = *(const short8*)&Ag[sp][(size_t)(m0 + r) * 1024 + k0 + 32 + skq * 8];
                    rbv[sp][i] = *(const short8*)&Bg[sp][(size_t)(n0 + r) * 1024 + k0 + 32 + skq * 8];
                }
        }

        short8 af[3][4];
#pragma unroll
        for (int mi = 0; mi < 4; ++mi) {
            int ro = (wr + mi * 16 + l15) * 48 + ko;
#pragma unroll
            for (int sp = 0; sp < 3; ++sp) af[sp][mi] = *(const short8*)&Asl[sp][ro];
        }
#pragma unroll
        for (int ni = 0; ni < 4; ++ni) {
            int co = (wc + ni * 16 + l15) * 48 + ko;
            short8 b0 = *(const short8*)&Bsl[0][co];
            short8 b1 = *(const short8*)&Bsl[1][co];
            short8 b2 = *(const short8*)&Bsl[2][co];
#pragma unroll
            for (int mi = 0; mi < 4; ++mi) {
                f32x4 a = acc[mi][ni];
                a = __builtin_amdgcn_mfma_f32_16x16x32_bf16(af[0][mi], b0, a, 0, 0, 0);
                a = __builtin_amdgcn_mfma_f32_16x16x32_bf16(af[1][mi], b0, a, 0, 0, 0);
                a = __builtin_amdgcn_mfma_f32_16x16x32_bf16(af[0][mi], b1, a, 0, 0, 0);
                a = __builtin_amdgcn_mfma_f32_16x16x32_bf16(af[2][mi], b0, a, 0, 0, 0);
                a = __builtin_amdgcn_mfma_f32_16x16x32_bf16(af[1][mi], b1, a, 0, 0, 0);
                a = __builtin_amdgcn_mfma_f32_16x16x32_bf16(af[0][mi], b2, a, 0, 0, 0);
                acc[mi][ni] = a;
            }
        }
        __syncthreads();
    }

#pragma unroll
    for (int ni = 0; ni < 4; ++ni) {
        int col = n0 + wc + ni * 16 + l15;
        float bv = bias[col];
#pragma unroll
        for (int mi = 0; mi < 4; ++mi) {
            int rbase = m0 + wr + mi * 16 + (lane >> 4) * 4;
#pragma unroll
            for (int r = 0; r < 4; ++r) {
                int m = rbase + r;
                if (MODE == 0) {
                    C[(size_t)m * 4096 + col] = acc[mi][ni][r] + bv;
                } else {
                    int t = m >> 5, b = m & 31;
                    C[((size_t)b * TT + t) * HH + col] = acc[mi][ni][r] + bv;
                }
            }
        }
    }
}

// ---------- MFMA bf16x3 GEMM, fp32 A split in-kernel (R10 proven; fallback tier) ----------
__global__ __launch_bounds__(256, 2) void k_gemm_mx3(const float* __restrict__ A,
                                                     const unsigned short* __restrict__ B1,
                                                     const unsigned short* __restrict__ B2,
                                                     const unsigned short* __restrict__ B3,
                                                     const float* __restrict__ bias, float* __restrict__ C) {
    __shared__ unsigned short Asl[3][6144];
    __shared__ unsigned short Bsl[3][6144];
    int tid = threadIdx.x;
    int m0 = blockIdx.x * 128, n0 = blockIdx.y * 128;
    int lane = tid & 63, wv = tid >> 6;
    int wr = (wv >> 1) * 64, wc = (wv & 1) * 64;
    int l15 = lane & 15, ko = (lane >> 4) * 8;

    f32x4 acc[4][4];
#pragma unroll
    for (int i = 0; i < 4; ++i)
#pragma unroll
        for (int j = 0; j < 4; ++j) acc[i][j] = (f32x4){0.f, 0.f, 0.f, 0.f};

    const unsigned short* Bg[3] = {B1, B2, B3};

    for (int k0 = 0; k0 < 1024; k0 += 32) {
#pragma unroll
        for (int i = 0; i < 4; ++i) {
            int idx = i * 256 + tid;
            int m = idx >> 3, kq = idx & 7;
            float4 v = *(const float4*)&A[(size_t)(m0 + m) * 1024 + k0 + kq * 4];
            float xs[4] = {v.x, v.y, v.z, v.w};
            ushort4 o1, o2, o3;
            unsigned short* po1 = (unsigned short*)&o1;
            unsigned short* po2 = (unsigned short*)&o2;
            unsigned short* po3 = (unsigned short*)&o3;
#pragma unroll
            for (int e = 0; e < 4; ++e) {
                unsigned short s1 = rne_bf16(xs[e]);
                float r1 = xs[e] - bf16f(s1);
                unsigned short s2 = rne_bf16(r1);
                float r2 = r1 - bf16f(s2);
                po1[e] = s1; po2[e] = s2; po3[e] = rne_bf16(r2);
            }
            int loff = m * 48 + kq * 4;
            *(ushort4*)&Asl[0][loff] = o1;
            *(ushort4*)&Asl[1][loff] = o2;
            *(ushort4*)&Asl[2][loff] = o3;
        }
#pragma unroll
        for (int sp = 0; sp < 3; ++sp) {
            const unsigned short* bg = Bg[sp];
#pragma unroll
            for (int i = 0; i < 2; ++i) {
                int idx = i * 256 + tid;
                int n = idx >> 2, kq = idx & 3;
                short8 v = *(const short8*)&bg[(size_t)(n0 + n) * 1024 + k0 + kq * 8];
                *(short8*)&Bsl[sp][n * 48 + kq * 8] = v;
            }
        }
        __syncthreads();

        short8 af[3][4];
#pragma unroll
        for (int mi = 0; mi < 4; ++mi) {
            int ro = (wr + mi * 16 + l15) * 48 + ko;
#pragma unroll
            for (int sp = 0; sp < 3; ++sp) af[sp][mi] = *(const short8*)&Asl[sp][ro];
        }
#pragma unroll
        for (int ni = 0; ni < 4; ++ni) {
            int co = (wc + ni * 16 + l15) * 48 + ko;
            short8 b0 = *(const short8*)&Bsl[0][co];
            short8 b1 = *(const short8*)&Bsl[1][co];
            short8 b2 = *(const short8*)&Bsl[2][co];
#pragma unroll
            for (int mi = 0; mi < 4; ++mi) {
                f32x4 a = acc[mi][ni];
                a = __builtin_amdgcn_mfma_f32_16x16x32_bf16(af[0][mi], b0, a, 0, 0, 0);
                a = __builtin_amdgcn_mfma_f32_16x16x32_bf16(af[1][mi], b0, a, 0, 0, 0);
                a = __builtin_amdgcn_mfma_f32_16x16x32_bf16(af[0][mi], b1, a, 0, 0, 0);
                a = __builtin_amdgcn_mfma_f32_16x16x32_bf16(af[2][mi], b0, a, 0, 0, 0);
                a = __builtin_amdgcn_mfma_f32_16x16x32_bf16(af[1][mi], b1, a, 0, 0, 0);
                a = __builtin_amdgcn_mfma_f32_16x16x32_bf16(af[0][mi], b2, a, 0, 0, 0);
                acc[mi][ni] = a;
            }
        }
        __syncthreads();
    }

#pragma unroll
    for (int ni = 0; ni < 4; ++ni) {
        int col = n0 + wc + ni * 16 + l15;
        float bv = bias[col];
#pragma unroll
        for (int mi = 0; mi < 4; ++mi) {
            int rbase = m0 + wr + mi * 16 + (lane >> 4) * 4;
#pragma unroll
            for (int r = 0; r < 4; ++r)
                C[(size_t)(rbase + r) * 4096 + col] = acc[mi][ni][r] + bv;
        }
    }
}

// ---------- fp32 GEMM (deep fallback): C = A@W + bias ----------
template <int MODE>
__global__ __launch_bounds__(256) void k_gemm(const float* __restrict__ A, const float* __restrict__ W,
                                              const float* __restrict__ bias, float* __restrict__ C, int N) {
    __shared__ float As[16][132];
    __shared__ float Bs[16][132];
    const int K = 1024;
    int tid = threadIdx.x;
    int m0 = blockIdx.x * 128, n0 = blockIdx.y * 128;
    int tx = tid & 15, ty = tid >> 4;
    int a_row = tid >> 2, a_kq = tid & 3;
    int b_cq = tid & 31, b_k = tid >> 5;
    float acc[8][8];
#pragma unroll
    for (int i = 0; i < 8; ++i)
#pragma unroll
        for (int jj = 0; jj < 8; ++jj) acc[i][jj] = 0.f;

    for (int kc = 0; kc < K; kc += 16) {
#pragma unroll
        for (int it = 0; it < 2; ++it) {
            int row = a_row + it * 64;
            float4 v = *(const float4*)&A[(size_t)(m0 + row) * K + kc + a_kq * 4];
            As[a_kq * 4 + 0][row] = v.x;
            As[a_kq * 4 + 1][row] = v.y;
            As[a_kq * 4 + 2][row] = v.z;
            As[a_kq * 4 + 3][row] = v.w;
        }
#pragma unroll
        for (int it = 0; it < 2; ++it) {
            int kk = b_k + it * 8;
            float4 v = *(const float4*)&W[(size_t)(kc + kk) * N + n0 + b_cq * 4];
            *(float4*)&Bs[kk][b_cq * 4] = v;
        }
        __syncthreads();
#pragma unroll
        for (int kk = 0; kk < 16; ++kk) {
            float4 a0 = *(const float4*)&As[kk][ty * 8];
            float4 a1 = *(const float4*)&As[kk][ty * 8 + 4];
            float4 b0 = *(const float4*)&Bs[kk][tx * 8];
            float4 b1 = *(const float4*)&Bs[kk][tx * 8 + 4];
            float am[8] = {a0.x, a0.y, a0.z, a0.w, a1.x, a1.y, a1.z, a1.w};
            float bv[8] = {b0.x, b0.y, b0.z, b0.w, b1.x, b1.y, b1.z, b1.w};
#pragma unroll
            for (int i = 0; i < 8; ++i)
#pragma unroll
                for (int jj = 0; jj < 8; ++jj) acc[i][jj] += am[i] * bv[jj];
        }
        __syncthreads();
    }
#pragma unroll
    for (int i = 0; i < 8; ++i) {
        int m = m0 + ty * 8 + i;
#pragma unroll
        for (int jj = 0; jj < 8; jj += 4) {
            int n = n0 + tx * 8 + jj;
            float4 v;
            v.x = acc[i][jj + 0] + bias[n + 0];
            v.y = acc[i][jj + 1] + bias[n + 1];
            v.z = acc[i][jj + 2] + bias[n + 2];
            v.w = acc[i][jj + 3] + bias[n + 3];
            if (MODE == 0) {
                *(float4*)&C[(size_t)m * N + n] = v;
            } else {
                int t = m >> 5, b = m & 31;
                *(float4*)&C[((size_t)b * TT + t) * HH + n] = v;
            }
        }
    }
}

// ---------- one LSTM timestep via MFMA, 128 blocks x 8 h-cols ----------
// Block nb owns h-cols nb*8+e (e=0..7) = two 4-col groups cg=e>>2 (wrb rows
// (nb*2+cg)*16 + g*4+d). Per-wave k-slices and all summation orders identical to
// the proven 256-block version -> bit-identical numerics. Halves WG count and
// broadcast-h L2 pressure.
__global__ __launch_bounds__(512) void k_step_mfma8(
    const unsigned short* __restrict__ Wb1, const unsigned short* __restrict__ Wb2,
    const unsigned short* __restrict__ Wb3,
    const unsigned short* __restrict__ Ha1, const unsigned short* __restrict__ Ha2,
    const unsigned short* __restrict__ Ha3,
    unsigned short* __restrict__ Ho1, unsigned short* __restrict__ Ho2,
    unsigned short* __restrict__ Ho3,
    const float* __restrict__ xw_t,
    unsigned short* __restrict__ sq1, unsigned short* __restrict__ sq2,
    unsigned short* __restrict__ sq3, float* __restrict__ seq_t,
    float* __restrict__ h_out, float* __restrict__ c) {
    __shared__ float zs[8][2][16][33];
    int tid = threadIdx.x;
    int lane = tid & 63, wv = tid >> 6;
    int nb = blockIdx.x;
    int l15 = lane & 15, ko = (lane >> 4) * 8;

    // xw prefetch (epilogue operand): 256 reducer threads, (rb, e)
    int rb = tid >> 3, e8 = tid & 7;
    float pz[4];
    if (tid < 256) {
#pragma unroll
        for (int g = 0; g < 4; ++g) pz[g] = xw_t[rb * GG + g * HH + nb * 8 + e8];
    }

    size_t abase0 = (size_t)l15 * 1024 + ko;          // batches 0..15
    size_t abase1 = (size_t)(16 + l15) * 1024 + ko;   // batches 16..31

    f32x4 acc[2][2];                                   // [cg][batch-group]
#pragma unroll
    for (int i = 0; i < 2; ++i)
#pragma unroll
        for (int j = 0; j < 2; ++j) acc[i][j] = (f32x4){0.f, 0.f, 0.f, 0.f};

#pragma unroll
    for (int kt = 0; kt < 4; ++kt) {
        int kk = (wv * 4 + kt) * 32;
        short8 a00 = *(const short8*)&Ha1[abase0 + kk];
        short8 a01 = *(const short8*)&Ha2[abase0 + kk];
        short8 a02 = *(const short8*)&Ha3[abase0 + kk];
        short8 a10 = *(const short8*)&Ha1[abase1 + kk];
        short8 a11 = *(const short8*)&Ha2[abase1 + kk];
        short8 a12 = *(const short8*)&Ha3[abase1 + kk];
#pragma unroll
        for (int cg = 0; cg < 2; ++cg) {
            size_t bbase = ((size_t)(nb * 2 + cg) * 16 + l15) * 1024 + ko;
            short8 b0 = *(const short8*)&Wb1[bbase + kk];
            short8 b1 = *(const short8*)&Wb2[bbase + kk];
            short8 b2 = *(const short8*)&Wb3[bbase + kk];
            f32x4 a0 = acc[cg][0];
            a0 = __builtin_amdgcn_mfma_f32_16x16x32_bf16(a00, b0, a0, 0, 0, 0);
            a0 = __builtin_amdgcn_mfma_f32_16x16x32_bf16(a01, b0, a0, 0, 0, 0);
            a0 = __builtin_amdgcn_mfma_f32_16x16x32_bf16(a00, b1, a0, 0, 0, 0);
            a0 = __builtin_amdgcn_mfma_f32_16x16x32_bf16(a02, b0, a0, 0, 0, 0);
            a0 = __builtin_amdgcn_mfma_f32_16x16x32_bf16(a01, b1, a0, 0, 0, 0);
            a0 = __builtin_amdgcn_mfma_f32_16x16x32_bf16(a00, b2, a0, 0, 0, 0);
            acc[cg][0] = a0;
            f32x4 a1 = acc[cg][1];
            a1 = __builtin_amdgcn_mfma_f32_16x16x32_bf16(a10, b0, a1, 0, 0, 0);
            a1 = __builtin_amdgcn_mfma_f32_16x16x32_bf16(a11, b0, a1, 0, 0, 0);
            a1 = __builtin_amdgcn_mfma_f32_16x16x32_bf16(a10, b1, a1, 0, 0, 0);
            a1 = __builtin_amdgcn_mfma_f32_16x16x32_bf16(a12, b0, a1, 0, 0, 0);
            a1 = __builtin_amdgcn_mfma_f32_16x16x32_bf16(a11, b1, a1, 0, 0, 0);
            a1 = __builtin_amdgcn_mfma_f32_16x16x32_bf16(a10, b2, a1, 0, 0, 0);
            acc[cg][1] = a1;
        }
    }

    // partials -> LDS (D layout: col=lane&15, row=(lane>>4)*4+r)
#pragma unroll
    for (int cg = 0; cg < 2; ++cg)
#pragma unroll
        for (int r = 0; r < 4; ++r) {
            zs[wv][cg][l15][(lane >> 4) * 4 + r]      = acc[cg][0][r];
            zs[wv][cg][l15][16 + (lane >> 4) * 4 + r] = acc[cg][1][r];
        }
    __syncthreads();

    // epilogue: 256 reducers, same 8-wave sum order as proven version
    if (tid < 256) {
        int cg = e8 >> 2, d = e8 & 3;
        float zz[4];
#pragma unroll
        for (int g = 0; g < 4; ++g) {
            float s = pz[g];
#pragma unroll
            for (int u = 0; u < 8; ++u) s += zs[u][cg][g * 4 + d][rb];
            zz[g] = s;
        }
        float si = 1.f / (1.f + expf(-zz[0]));
        float sf = 1.f / (1.f + expf(-zz[1]));
        float gg = fmaxf(zz[2], 0.f);
        float so = 1.f / (1.f + expf(-zz[3]));
        int hi = rb * HH + nb * 8 + e8;
        float cv = c[hi];
        cv = sf * cv + si * gg;
        c[hi] = cv;
        float hn = so * fmaxf(cv, 0.f);
        h_out[hi] = hn;
        unsigned short s1 = rne_bf16(hn);
        float r1 = hn - bf16f(s1);
        unsigned short s2 = rne_bf16(r1);
        float r2 = r1 - bf16f(s2);
        unsigned short s3 = rne_bf16(r2);
        Ho1[hi] = s1; Ho2[hi] = s2; Ho3[hi] = s3;
        if (sq1) {
            sq1[hi] = s1; sq2[hi] = s2; sq3[hi] = s3;
        } else {
            seq_t[hi] = hn;
        }
    }
}

// ---------- R9 step (fp32 WrT, 512 thr) — fallback ----------
__global__ __launch_bounds__(512) void k_step_T3(const float* __restrict__ WrT, const float* __restrict__ xw_t,
                                                 float* __restrict__ seq_t, const float* __restrict__ h_in,
                                                 float* __restrict__ h_out, float* __restrict__ c) {
    __shared__ float h_lds[34816];
    __shared__ float zred[8][32][17];
    int tid = threadIdx.x;
    int j = tid & 15, ks = tid >> 4;
    int hc0 = blockIdx.x * 4;
    int col = (j >> 2) * HH + hc0 + (j & 3);

    const float4* WrT4 = (const float4*)WrT;
    int wbase = col * 256 + ks * 8;
    float4 w[8];
#pragma unroll
    for (int q = 0; q < 8; ++q) w[q] = WrT4[wbase + q];

    int rb = tid >> 2, rd = tid & 3;
    float pz[4];
    if (tid < 128) {
#pragma unroll
        for (int g = 0; g < 4; ++g) pz[g] = xw_t[rb * GG + g * HH + hc0 + rd];
    }

    const float4* hp4 = (const float4*)h_in;
    float4* hl4w = (float4*)h_lds;
#pragma unroll 8
    for (int it = 0; it < 16; ++it) {
        int gi = it * 512 + tid;
        float4 v = hp4[gi];
        int b = gi >> 8, kk = gi & 255;
        hl4w[b * 272 + (kk >> 4) * 17 + (kk & 15)] = v;
    }
    __syncthreads();

    const float4* hl4 = (const float4*)h_lds;
    int base4 = (ks >> 1) * 17 + (ks & 1) * 8;
    float acc[32];
#pragma unroll
    for (int b = 0; b < 32; ++b) acc[b] = 0.f;
#pragma unroll
    for (int q = 0; q < 8; ++q) {
        float4 wq = w[q];
#pragma unroll
        for (int b = 0; b < 32; ++b) {
            float4 hv = hl4[b * 272 + base4 + q];
            acc[b] += wq.x * hv.x + wq.y * hv.y + wq.z * hv.z + wq.w * hv.w;
        }
    }
#pragma unroll
    for (int b = 0; b < 32; ++b) {
        acc[b] += __shfl_xor(acc[b], 16);
        acc[b] += __shfl_xor(acc[b], 32);
    }
    int wv = tid >> 6;
    if ((ks & 3) == 0) {
#pragma unroll
        for (int b = 0; b < 32; ++b) zred[wv][b][j] = acc[b];
    }
    __syncthreads();

    if (tid < 128) {
        float zz[4];
#pragma unroll
        for (int g = 0; g < 4; ++g) {
            float s = pz[g];
#pragma unroll
            for (int u = 0; u < 8; ++u) s += zred[u][rb][g * 4 + rd];
            zz[g] = s;
        }
        float si = 1.f / (1.f + expf(-zz[0]));
        float sf = 1.f / (1.f + expf(-zz[1]));
        float gg = fmaxf(zz[2], 0.f);
        float so = 1.f / (1.f + expf(-zz[3]));
        float cv = c[rb * HH + hc0 + rd];
        cv = sf * cv + si * gg;
        c[rb * HH + hc0 + rd] = cv;
        float hn = so * fmaxf(cv, 0.f);
        h_out[rb * HH + hc0 + rd] = hn;
        seq_t[rb * HH + hc0 + rd] = hn;
    }
}

// ---------- R2 fallback step (row-major Wr, 256 thr) ----------
__global__ __launch_bounds__(256) void k_step(const float* __restrict__ Wr, const float* __restrict__ xw_t,
                                              float* __restrict__ seq_t, const float* __restrict__ h_in,
                                              float* __restrict__ h_out, float* __restrict__ c) {
    __shared__ float zred[4][32][17];
    int tid = threadIdx.x;
    int j = tid & 15, ks = tid >> 4;
    int hc0 = blockIdx.x * 4;
    int col = (j >> 2) * HH + hc0 + (j & 3);
    float4 w[16];
#pragma unroll
    for (int q = 0; q < 16; ++q) {
        size_t kb = (size_t)(ks * 64 + q * 4) * GG + col;
        w[q].x = Wr[kb];
        w[q].y = Wr[kb + GG];
        w[q].z = Wr[kb + 2 * (size_t)GG];
        w[q].w = Wr[kb + 3 * (size_t)GG];
    }
    const float4* hp = (const float4*)h_in;
    int kq0 = ks * 16;
    float acc[32];
#pragma unroll
    for (int b = 0; b < 32; ++b) acc[b] = 0.f;
#pragma unroll
    for (int q = 0; q < 16; ++q) {
        float4 wq = w[q];
#pragma unroll
        for (int b = 0; b < 32; ++b) {
            float4 hv = hp[b * 256 + kq0 + q];
            acc[b] += wq.x * hv.x + wq.y * hv.y + wq.z * hv.z + wq.w * hv.w;
        }
    }
#pragma unroll
    for (int b = 0; b < 32; ++b) {
        acc[b] += __shfl_xor(acc[b], 16);
        acc[b] += __shfl_xor(acc[b], 32);
    }
    int wv = tid >> 6;
    if ((ks & 3) == 0) {
#pragma unroll
        for (int b = 0; b < 32; ++b) zred[wv][b][j] = acc[b];
    }
    __syncthreads();
    if (tid < 128) {
        int rb = tid >> 2, rd = tid & 3;
        float zz[4];
#pragma unroll
        for (int g = 0; g < 4; ++g) {
            float s = xw_t[rb * GG + g * HH + hc0 + rd];
#pragma unroll
            for (int u = 0; u < 4; ++u) s += zred[u][rb][g * 4 + rd];
            zz[g] = s;
        }
        float si = 1.f / (1.f + expf(-zz[0]));
        float sf = 1.f / (1.f + expf(-zz[1]));
        float gg = fmaxf(zz[2], 0.f);
        float so = 1.f / (1.f + expf(-zz[3]));
        float cv = c[rb * HH + hc0 + rd];
        cv = sf * cv + si * gg;
        c[rb * HH + hc0 + rd] = cv;
        float hn = so * fmaxf(cv, 0.f);
        h_out[rb * HH + hc0 + rd] = hn;
        seq_t[rb * HH + hc0 + rd] = hn;
    }
}

extern "C" void kernel_launch(void* const* d_in, const int* in_sizes, int n_in,
                              void* d_out, int out_size, void* d_ws, size_t ws_size,
                              hipStream_t stream) {
    const float* x  = (const float*)d_in[0];
    const float* h0 = (const float*)d_in[1];
    const float* c0 = (const float*)d_in[2];
    const float* Wk = (const float*)d_in[3];
    const float* Wr = (const float*)d_in[4];
    const float* bs = (const float*)d_in[5];
    const float* Wd = (const float*)d_in[6];
    const float* bd = (const float*)d_in[7];
    float* out = (float*)d_out;
    float* ws  = (float*)d_ws;

    float* xw  = ws;                         // [T][B][4H]  (128 MB)
    float* seq = ws + 33554432;              // [T][B][H] fp32 (fallback) / sq1+sq2 alias
    float* h0b = seq + 8388608;
    float* h1b = h0b + 32768;
    float* c   = h1b + 32768;
    float* wrt = c + 32768;                  // fp32 WrT (fallback)
    const size_t base_floats = 46235648;
    unsigned short* wkt1 = (unsigned short*)(ws + base_floats);  // also Wd splits (head)
    unsigned short* wkt2 = wkt1 + 4194304;
    unsigned short* wkt3 = wkt2 + 4194304;
    unsigned short* wrb1 = wkt3 + 4194304;
    unsigned short* wrb2 = wrb1 + 4194304;
    unsigned short* wrb3 = wrb2 + 4194304;
    unsigned short* hA1  = wrb3 + 4194304;
    unsigned short* hA2  = hA1 + 32768;
    unsigned short* hA3  = hA2 + 32768;
    unsigned short* hB1  = hA3 + 32768;
    unsigned short* hB2  = hB1 + 32768;
    unsigned short* hB3  = hB2 + 32768;
    unsigned short* sq1  = (unsigned short*)seq;
    unsigned short* sq2  = sq1 + 8388608;
    unsigned short* sq3  = hB3 + 32768;

    const size_t mfma2_floats = base_floats + ((size_t)6 * 4194304 * 2 + 6 * 32768 * 2 + 3) / 4;
    const size_t mfma3_floats = mfma2_floats + ((size_t)8388608 * 2 + 3) / 4;
    bool fast     = ws_size >= base_floats * 4;
    bool mfma_ok  = ws_size >= base_floats * 4 + (size_t)3 * 4194304 * 2;
    bool mfma2_ok = ws_size >= mfma2_floats * 4;
    bool mfma3_ok = ws_size >= mfma3_floats * 4;

    if (mfma3_ok) {
        k_transpose3<<<8192, 256, 0, stream>>>(x, sq1, sq2, sq3);
        k_init_hc2<<<32, 256, 0, stream>>>(h0, c0, h0b, c, hA1, hA2, hA3);
    } else {
        k_transpose<<<8192, 256, 0, stream>>>(x, seq);
        if (mfma2_ok)
            k_init_hc2<<<32, 256, 0, stream>>>(h0, c0, h0b, c, hA1, hA2, hA3);
        else
            k_init_hc<<<32, 256, 0, stream>>>(h0, c0, h0b, c);
    }

    for (int l = 0; l < 4; ++l) {
        const float* Wrl = Wr + (size_t)l * 1024 * 4096;
        const float* Wkl = Wk + (size_t)l * 1024 * 4096;
        if (mfma3_ok) {
            k_wt3<<<dim3(64, 16), 256, 0, stream>>>(Wkl, 4096, wkt1, wkt2, wkt3);
            k_gemm_mx3s<0><<<dim3(64, 32), 256, 0, stream>>>(sq1, sq2, sq3, wkt1, wkt2, wkt3,
                                                             bs + l * 4096, xw);
        } else if (mfma_ok) {
            k_wt3<<<dim3(64, 16), 256, 0, stream>>>(Wkl, 4096, wkt1, wkt2, wkt3);
            k_gemm_mx3<<<dim3(64, 32), 256, 0, stream>>>(seq, wkt1, wkt2, wkt3, bs + l * 4096, xw);
        } else {
            k_gemm<0><<<dim3(64, 32), 256, 0, stream>>>(seq, Wkl, bs + l * 4096, xw, 4096);
        }
        if (mfma2_ok) {
            k_wrt3<<<dim3(64, 16), 256, 0, stream>>>(Wrl, wrb1, wrb2, wrb3);
            for (int t = 0; t < TT; ++t) {
                float* hout = (t & 1) ? h0b : h1b;
                const unsigned short* i1 = (t & 1) ? hB1 : hA1;
                const unsigned short* i2 = (t & 1) ? hB2 : hA2;
                const unsigned short* i3 = (t & 1) ? hB3 : hA3;
                unsigned short* o1 = (t & 1) ? hA1 : hB1;
                unsigned short* o2 = (t & 1) ? hA2 : hB2;
                unsigned short* o3 = (t & 1) ? hA3 : hB3;
                if (mfma3_ok)
                    k_step_mfma8<<<128, 512, 0, stream>>>(wrb1, wrb2, wrb3, i1, i2, i3, o1, o2, o3,
                                                          xw + (size_t)t * (BB * GG),
                                                          sq1 + (size_t)t * (BB * HH),
                                                          sq2 + (size_t)t * (BB * HH),
                                                          sq3 + (size_t)t * (BB * HH),
                                                          nullptr, hout, c);
                else
                    k_step_mfma8<<<128, 512, 0, stream>>>(wrb1, wrb2, wrb3, i1, i2, i3, o1, o2, o3,
                                                          xw + (size_t)t * (BB * GG),
                                                          nullptr, nullptr, nullptr,
                                                          seq + (size_t)t * (BB * HH), hout, c);
            }
        } else {
            if (fast) k_wrt<<<dim3(64, 16), 256, 0, stream>>>(Wrl, wrt);
            for (int t = 0; t < TT; ++t) {
                const float* hin = (t & 1) ? h1b : h0b;
                float* hout      = (t & 1) ? h0b : h1b;
                if (fast)
                    k_step_T3<<<256, 512, 0, stream>>>(wrt, xw + (size_t)t * (BB * GG),
                                                       seq + (size_t)t * (BB * HH), hin, hout, c);
                else
                    k_step<<<256, 256, 0, stream>>>(Wrl, xw + (size_t)t * (BB * GG),
                                                    seq + (size_t)t * (BB * HH), hin, hout, c);
            }
        }
    }

    if (mfma3_ok) {
        k_wt3<<<dim3(16, 16), 256, 0, stream>>>(Wd, 1024, wkt1, wkt2, wkt3);
        k_gemm_mx3s<1><<<dim3(64, 8), 256, 0, stream>>>(sq1, sq2, sq3, wkt1, wkt2, wkt3, bd, out);
    } else {
        k_gemm<1><<<dim3(64, 8), 256, 0, stream>>>(seq, Wd, bd, out, 1024);
    }
    k_copy_hc<<<32, 256, 0, stream>>>(h0b, c, out + 8388608, out + 8388608 + 32768);
}

// Round 14
// 13475.111 us; speedup vs baseline: 1.1809x; 1.1809x over previous
//
#include <hip/hip_runtime.h>

#define TT 256
#define BB 32
#define HH 1024
#define GG 4096

typedef __attribute__((ext_vector_type(8))) short short8;
typedef __attribute__((ext_vector_type(4))) float f32x4;

__device__ __forceinline__ unsigned short rne_bf16(float x) {
    unsigned u = __float_as_uint(x);
    unsigned r = (u + 0x7FFFu + ((u >> 16) & 1u)) >> 16;
    return (unsigned short)r;
}
__device__ __forceinline__ float bf16f(unsigned short s) {
    return __uint_as_float((unsigned)s << 16);
}

// ---------- transpose x[B,T,H] -> seq[T,B,H] ----------
__global__ __launch_bounds__(256) void k_transpose(const float* __restrict__ x, float* __restrict__ seq) {
    int idx = blockIdx.x * 256 + threadIdx.x;
    int k4 = idx & 255;
    int tb = idx >> 8;
    int t = tb >> 5, b = tb & 31;
    float4 v = ((const float4*)x)[((size_t)b * TT + t) * 256 + k4];
    ((float4*)seq)[(size_t)tb * 256 + k4] = v;
}

__global__ __launch_bounds__(256) void k_init_hc(const float* __restrict__ h0, const float* __restrict__ c0,
                                                 float* __restrict__ h, float* __restrict__ c) {
    int i = blockIdx.x * 256 + threadIdx.x;
    ((float4*)h)[i] = ((const float4*)h0)[i];
    ((float4*)c)[i] = ((const float4*)c0)[i];
}

// init + bf16x3 split of h0 (for the MFMA scan path)
__global__ __launch_bounds__(256) void k_init_hc2(const float* __restrict__ h0, const float* __restrict__ c0,
                                                  float* __restrict__ h, float* __restrict__ c,
                                                  unsigned short* __restrict__ hb1,
                                                  unsigned short* __restrict__ hb2,
                                                  unsigned short* __restrict__ hb3) {
    int i = blockIdx.x * 256 + threadIdx.x;
    float4 hv = ((const float4*)h0)[i];
    ((float4*)h)[i] = hv;
    ((float4*)c)[i] = ((const float4*)c0)[i];
    float xs[4] = {hv.x, hv.y, hv.z, hv.w};
    ushort4 o1, o2, o3;
    unsigned short* p1 = (unsigned short*)&o1;
    unsigned short* p2 = (unsigned short*)&o2;
    unsigned short* p3 = (unsigned short*)&o3;
#pragma unroll
    for (int e = 0; e < 4; ++e) {
        unsigned short s1 = rne_bf16(xs[e]);
        float r1 = xs[e] - bf16f(s1);
        unsigned short s2 = rne_bf16(r1);
        float r2 = r1 - bf16f(s2);
        p1[e] = s1; p2[e] = s2; p3[e] = rne_bf16(r2);
    }
    *(ushort4*)&hb1[i * 4] = o1;
    *(ushort4*)&hb2[i * 4] = o2;
    *(ushort4*)&hb3[i * 4] = o3;
}

__global__ __launch_bounds__(256) void k_copy_hc(const float* __restrict__ h, const float* __restrict__ c,
                                                 float* __restrict__ oh, float* __restrict__ oc) {
    int i = blockIdx.x * 256 + threadIdx.x;
    ((float4*)oh)[i] = ((const float4*)h)[i];
    ((float4*)oc)[i] = ((const float4*)c)[i];
}

// ---------- Wr[1024,4096] -> WrT[4096,1024] fp32 (fallback scan path) ----------
__global__ __launch_bounds__(256) void k_wrt(const float* __restrict__ Wr, float* __restrict__ WrT) {
    __shared__ float tile[64][65];
    int c0 = blockIdx.x * 64;
    int k0 = blockIdx.y * 64;
    int tid = threadIdx.x;
    int tr = tid >> 4, tc4 = tid & 15;
#pragma unroll
    for (int p = 0; p < 4; ++p) {
        int r = p * 16 + tr;
        float4 v = *(const float4*)&Wr[(size_t)(k0 + r) * GG + c0 + tc4 * 4];
        tile[r][tc4 * 4 + 0] = v.x;
        tile[r][tc4 * 4 + 1] = v.y;
        tile[r][tc4 * 4 + 2] = v.z;
        tile[r][tc4 * 4 + 3] = v.w;
    }
    __syncthreads();
#pragma unroll
    for (int p = 0; p < 4; ++p) {
        int cc = p * 16 + tr;
        float4 v;
        v.x = tile[tc4 * 4 + 0][cc];
        v.y = tile[tc4 * 4 + 1][cc];
        v.z = tile[tc4 * 4 + 2][cc];
        v.w = tile[tc4 * 4 + 3][cc];
        *(float4*)&WrT[(size_t)(c0 + cc) * 1024 + k0 + tc4 * 4] = v;
    }
}

// ---------- Wr -> gate-permuted bf16x3 wrb[blk][16(g*4+d)][1024 k] ----------
__global__ __launch_bounds__(256) void k_wrt3(const float* __restrict__ Wr, unsigned short* __restrict__ W1,
                                              unsigned short* __restrict__ W2, unsigned short* __restrict__ W3) {
    __shared__ float tile[64][65];
    int c0 = blockIdx.x * 64;   // global col tile
    int k0 = blockIdx.y * 64;   // k tile
    int tid = threadIdx.x;
    int tr = tid >> 4, tc4 = tid & 15;
#pragma unroll
    for (int p = 0; p < 4; ++p) {
        int r = p * 16 + tr;
        float4 v = *(const float4*)&Wr[(size_t)(k0 + r) * GG + c0 + tc4 * 4];
        tile[r][tc4 * 4 + 0] = v.x;
        tile[r][tc4 * 4 + 1] = v.y;
        tile[r][tc4 * 4 + 2] = v.z;
        tile[r][tc4 * 4 + 3] = v.w;
    }
    __syncthreads();
    int cc = tid & 63, kq = tid >> 6;              // column within tile, 16-k chunk
    int G = c0 + cc;
    int outrow = ((G & 1023) >> 2) * 16 + (G >> 10) * 4 + (G & 3);  // blk*16 + g*4 + d
    size_t obase = (size_t)outrow * 1024 + k0 + kq * 16;
    unsigned short t1[16], t2[16], t3[16];
#pragma unroll
    for (int e = 0; e < 16; ++e) {
        float v = tile[kq * 16 + e][cc];
        unsigned short s1 = rne_bf16(v);
        float r1 = v - bf16f(s1);
        unsigned short s2 = rne_bf16(r1);
        float r2 = r1 - bf16f(s2);
        t1[e] = s1; t2[e] = s2; t3[e] = rne_bf16(r2);
    }
#pragma unroll
    for (int hlf = 0; hlf < 2; ++hlf) {
        *(short8*)&W1[obase + hlf * 8] = *(short8*)&t1[hlf * 8];
        *(short8*)&W2[obase + hlf * 8] = *(short8*)&t2[hlf * 8];
        *(short8*)&W3[obase + hlf * 8] = *(short8*)&t3[hlf * 8];
    }
}

// ---------- Wk[1024,4096] -> 3x bf16-split WkT[4096,1024] (proven R10) ----------
__global__ __launch_bounds__(256) void k_wkt3(const float* __restrict__ Wk, unsigned short* __restrict__ W1,
                                              unsigned short* __restrict__ W2, unsigned short* __restrict__ W3) {
    __shared__ float tile[64][65];
    int c0 = blockIdx.x * 64;
    int k0 = blockIdx.y * 64;
    int tid = threadIdx.x;
    int tr = tid >> 4, tc4 = tid & 15;
#pragma unroll
    for (int p = 0; p < 4; ++p) {
        int r = p * 16 + tr;
        float4 v = *(const float4*)&Wk[(size_t)(k0 + r) * GG + c0 + tc4 * 4];
        tile[r][tc4 * 4 + 0] = v.x;
        tile[r][tc4 * 4 + 1] = v.y;
        tile[r][tc4 * 4 + 2] = v.z;
        tile[r][tc4 * 4 + 3] = v.w;
    }
    __syncthreads();
#pragma unroll
    for (int p = 0; p < 4; ++p) {
        int cc = p * 16 + tr;
        ushort4 o1, o2, o3;
        unsigned short* po1 = (unsigned short*)&o1;
        unsigned short* po2 = (unsigned short*)&o2;
        unsigned short* po3 = (unsigned short*)&o3;
#pragma unroll
        for (int e = 0; e < 4; ++e) {
            float v = tile[tc4 * 4 + e][cc];
            unsigned short s1 = rne_bf16(v);
            float r1 = v - bf16f(s1);
            unsigned short s2 = rne_bf16(r1);
            float r2 = r1 - bf16f(s2);
            po1[e] = s1; po2[e] = s2; po3[e] = rne_bf16(r2);
        }
        size_t off = (size_t)(c0 + cc) * 1024 + k0 + tc4 * 4;
        *(ushort4*)&W1[off] = o1;
        *(ushort4*)&W2[off] = o2;
        *(ushort4*)&W3[off] = o3;
    }
}

// ---------- MFMA bf16x3 GEMM: xw = seq @ Wk + bias (proven R10) ----------
__global__ __launch_bounds__(256, 2) void k_gemm_mx3(const float* __restrict__ A,
                                                     const unsigned short* __restrict__ B1,
                                                     const unsigned short* __restrict__ B2,
                                                     const unsigned short* __restrict__ B3,
                                                     const float* __restrict__ bias, float* __restrict__ C) {
    __shared__ unsigned short Asl[3][6144];
    __shared__ unsigned short Bsl[3][6144];
    int tid = threadIdx.x;
    int m0 = blockIdx.x * 128, n0 = blockIdx.y * 128;
    int lane = tid & 63, wv = tid >> 6;
    int wr = (wv >> 1) * 64, wc = (wv & 1) * 64;
    int l15 = lane & 15, ko = (lane >> 4) * 8;

    f32x4 acc[4][4];
#pragma unroll
    for (int i = 0; i < 4; ++i)
#pragma unroll
        for (int j = 0; j < 4; ++j) acc[i][j] = (f32x4){0.f, 0.f, 0.f, 0.f};

    const unsigned short* Bg[3] = {B1, B2, B3};

    for (int k0 = 0; k0 < 1024; k0 += 32) {
#pragma unroll
        for (int i = 0; i < 4; ++i) {
            int idx = i * 256 + tid;
            int m = idx >> 3, kq = idx & 7;
            float4 v = *(const float4*)&A[(size_t)(m0 + m) * 1024 + k0 + kq * 4];
            float xs[4] = {v.x, v.y, v.z, v.w};
            ushort4 o1, o2, o3;
            unsigned short* po1 = (unsigned short*)&o1;
            unsigned short* po2 = (unsigned short*)&o2;
            unsigned short* po3 = (unsigned short*)&o3;
#pragma unroll
            for (int e = 0; e < 4; ++e) {
                unsigned short s1 = rne_bf16(xs[e]);
                float r1 = xs[e] - bf16f(s1);
                unsigned short s2 = rne_bf16(r1);
                float r2 = r1 - bf16f(s2);
                po1[e] = s1; po2[e] = s2; po3[e] = rne_bf16(r2);
            }
            int loff = m * 48 + kq * 4;
            *(ushort4*)&Asl[0][loff] = o1;
            *(ushort4*)&Asl[1][loff] = o2;
            *(ushort4*)&Asl[2][loff] = o3;
        }
#pragma unroll
        for (int sp = 0; sp < 3; ++sp) {
            const unsigned short* bg = Bg[sp];
#pragma unroll
            for (int i = 0; i < 2; ++i) {
                int idx = i * 256 + tid;
                int n = idx >> 2, kq = idx & 3;
                short8 v = *(const short8*)&bg[(size_t)(n0 + n) * 1024 + k0 + kq * 8];
                *(short8*)&Bsl[sp][n * 48 + kq * 8] = v;
            }
        }
        __syncthreads();

        short8 af[3][4];
#pragma unroll
        for (int mi = 0; mi < 4; ++mi) {
            int ro = (wr + mi * 16 + l15) * 48 + ko;
#pragma unroll
            for (int sp = 0; sp < 3; ++sp) af[sp][mi] = *(const short8*)&Asl[sp][ro];
        }
#pragma unroll
        for (int ni = 0; ni < 4; ++ni) {
            int co = (wc + ni * 16 + l15) * 48 + ko;
            short8 b0 = *(const short8*)&Bsl[0][co];
            short8 b1 = *(const short8*)&Bsl[1][co];
            short8 b2 = *(const short8*)&Bsl[2][co];
#pragma unroll
            for (int mi = 0; mi < 4; ++mi) {
                f32x4 a = acc[mi][ni];
                a = __builtin_amdgcn_mfma_f32_16x16x32_bf16(af[0][mi], b0, a, 0, 0, 0);
                a = __builtin_amdgcn_mfma_f32_16x16x32_bf16(af[1][mi], b0, a, 0, 0, 0);
                a = __builtin_amdgcn_mfma_f32_16x16x32_bf16(af[0][mi], b1, a, 0, 0, 0);
                a = __builtin_amdgcn_mfma_f32_16x16x32_bf16(af[2][mi], b0, a, 0, 0, 0);
                a = __builtin_amdgcn_mfma_f32_16x16x32_bf16(af[1][mi], b1, a, 0, 0, 0);
                a = __builtin_amdgcn_mfma_f32_16x16x32_bf16(af[0][mi], b2, a, 0, 0, 0);
                acc[mi][ni] = a;
            }
        }
        __syncthreads();
    }

#pragma unroll
    for (int ni = 0; ni < 4; ++ni) {
        int col = n0 + wc + ni * 16 + l15;
        float bv = bias[col];
#pragma unroll
        for (int mi = 0; mi < 4; ++mi) {
            int rbase = m0 + wr + mi * 16 + (lane >> 4) * 4;
#pragma unroll
            for (int r = 0; r < 4; ++r)
                C[(size_t)(rbase + r) * 4096 + col] = acc[mi][ni][r] + bv;
        }
    }
}

// ---------- fp32 GEMM (fallback + head): C = A@W + bias ----------
template <int MODE>
__global__ __launch_bounds__(256) void k_gemm(const float* __restrict__ A, const float* __restrict__ W,
                                              const float* __restrict__ bias, float* __restrict__ C, int N) {
    __shared__ float As[16][132];
    __shared__ float Bs[16][132];
    const int K = 1024;
    int tid = threadIdx.x;
    int m0 = blockIdx.x * 128, n0 = blockIdx.y * 128;
    int tx = tid & 15, ty = tid >> 4;
    int a_row = tid >> 2, a_kq = tid & 3;
    int b_cq = tid & 31, b_k = tid >> 5;
    float acc[8][8];
#pragma unroll
    for (int i = 0; i < 8; ++i)
#pragma unroll
        for (int jj = 0; jj < 8; ++jj) acc[i][jj] = 0.f;

    for (int kc = 0; kc < K; kc += 16) {
#pragma unroll
        for (int it = 0; it < 2; ++it) {
            int row = a_row + it * 64;
            float4 v = *(const float4*)&A[(size_t)(m0 + row) * K + kc + a_kq * 4];
            As[a_kq * 4 + 0][row] = v.x;
            As[a_kq * 4 + 1][row] = v.y;
            As[a_kq * 4 + 2][row] = v.z;
            As[a_kq * 4 + 3][row] = v.w;
        }
#pragma unroll
        for (int it = 0; it < 2; ++it) {
            int kk = b_k + it * 8;
            float4 v = *(const float4*)&W[(size_t)(kc + kk) * N + n0 + b_cq * 4];
            *(float4*)&Bs[kk][b_cq * 4] = v;
        }
        __syncthreads();
#pragma unroll
        for (int kk = 0; kk < 16; ++kk) {
            float4 a0 = *(const float4*)&As[kk][ty * 8];
            float4 a1 = *(const float4*)&As[kk][ty * 8 + 4];
            float4 b0 = *(const float4*)&Bs[kk][tx * 8];
            float4 b1 = *(const float4*)&Bs[kk][tx * 8 + 4];
            float am[8] = {a0.x, a0.y, a0.z, a0.w, a1.x, a1.y, a1.z, a1.w};
            float bv[8] = {b0.x, b0.y, b0.z, b0.w, b1.x, b1.y, b1.z, b1.w};
#pragma unroll
            for (int i = 0; i < 8; ++i)
#pragma unroll
                for (int jj = 0; jj < 8; ++jj) acc[i][jj] += am[i] * bv[jj];
        }
        __syncthreads();
    }
#pragma unroll
    for (int i = 0; i < 8; ++i) {
        int m = m0 + ty * 8 + i;
#pragma unroll
        for (int jj = 0; jj < 8; jj += 4) {
            int n = n0 + tx * 8 + jj;
            float4 v;
            v.x = acc[i][jj + 0] + bias[n + 0];
            v.y = acc[i][jj + 1] + bias[n + 1];
            v.z = acc[i][jj + 2] + bias[n + 2];
            v.w = acc[i][jj + 3] + bias[n + 3];
            if (MODE == 0) {
                *(float4*)&C[(size_t)m * N + n] = v;
            } else {
                int t = m >> 5, b = m & 31;
                *(float4*)&C[((size_t)b * TT + t) * HH + n] = v;
            }
        }
    }
}

// ---------- one LSTM timestep via MFMA (bf16x3-exact, proven R11 best) ----------
// 256 blocks x 512 threads. Block owns h-cols blk*4..+3 (16 gate cols, permuted
// contiguous in wrb). z[32,16] = h[32,1024] @ WrSlice via 16x16x32 MFMA; 8 waves
// k-split (128 k each); A (h) and B (Wr) read pre-split bf16x3 straight from global.
__global__ __launch_bounds__(512) void k_step_mfma(
    const unsigned short* __restrict__ Wb1, const unsigned short* __restrict__ Wb2,
    const unsigned short* __restrict__ Wb3,
    const unsigned short* __restrict__ Ha1, const unsigned short* __restrict__ Ha2,
    const unsigned short* __restrict__ Ha3,
    unsigned short* __restrict__ Ho1, unsigned short* __restrict__ Ho2,
    unsigned short* __restrict__ Ho3,
    const float* __restrict__ xw_t, float* __restrict__ seq_t,
    float* __restrict__ h_out, float* __restrict__ c) {
    __shared__ float zs[8][16][33];
    int tid = threadIdx.x;
    int lane = tid & 63, wv = tid >> 6;
    int blk = blockIdx.x;
    int l15 = lane & 15, ko = (lane >> 4) * 8;

    int rb = tid >> 2, rd = tid & 3;
    float pz[4];
    if (tid < 128) {
#pragma unroll
        for (int g = 0; g < 4; ++g) pz[g] = xw_t[rb * GG + g * HH + blk * 4 + rd];
    }

    size_t bbase  = ((size_t)blk * 16 + l15) * 1024 + ko;
    size_t abase0 = (size_t)l15 * 1024 + ko;
    size_t abase1 = (size_t)(16 + l15) * 1024 + ko;

    f32x4 acc0 = (f32x4){0.f, 0.f, 0.f, 0.f};
    f32x4 acc1 = (f32x4){0.f, 0.f, 0.f, 0.f};

#pragma unroll
    for (int kt = 0; kt < 4; ++kt) {
        int kk = (wv * 4 + kt) * 32;
        short8 b0  = *(const short8*)&Wb1[bbase + kk];
        short8 b1  = *(const short8*)&Wb2[bbase + kk];
        short8 b2  = *(const short8*)&Wb3[bbase + kk];
        short8 a00 = *(const short8*)&Ha1[abase0 + kk];
        short8 a01 = *(const short8*)&Ha2[abase0 + kk];
        short8 a02 = *(const short8*)&Ha3[abase0 + kk];
        short8 a10 = *(const short8*)&Ha1[abase1 + kk];
        short8 a11 = *(const short8*)&Ha2[abase1 + kk];
        short8 a12 = *(const short8*)&Ha3[abase1 + kk];
        acc0 = __builtin_amdgcn_mfma_f32_16x16x32_bf16(a00, b0, acc0, 0, 0, 0);
        acc0 = __builtin_amdgcn_mfma_f32_16x16x32_bf16(a01, b0, acc0, 0, 0, 0);
        acc0 = __builtin_amdgcn_mfma_f32_16x16x32_bf16(a00, b1, acc0, 0, 0, 0);
        acc0 = __builtin_amdgcn_mfma_f32_16x16x32_bf16(a02, b0, acc0, 0, 0, 0);
        acc0 = __builtin_amdgcn_mfma_f32_16x16x32_bf16(a01, b1, acc0, 0, 0, 0);
        acc0 = __builtin_amdgcn_mfma_f32_16x16x32_bf16(a00, b2, acc0, 0, 0, 0);
        acc1 = __builtin_amdgcn_mfma_f32_16x16x32_bf16(a10, b0, acc1, 0, 0, 0);
        acc1 = __builtin_amdgcn_mfma_f32_16x16x32_bf16(a11, b0, acc1, 0, 0, 0);
        acc1 = __builtin_amdgcn_mfma_f32_16x16x32_bf16(a10, b1, acc1, 0, 0, 0);
        acc1 = __builtin_amdgcn_mfma_f32_16x16x32_bf16(a12, b0, acc1, 0, 0, 0);
        acc1 = __builtin_amdgcn_mfma_f32_16x16x32_bf16(a11, b1, acc1, 0, 0, 0);
        acc1 = __builtin_amdgcn_mfma_f32_16x16x32_bf16(a10, b2, acc1, 0, 0, 0);
    }

#pragma unroll
    for (int r = 0; r < 4; ++r) {
        zs[wv][l15][(lane >> 4) * 4 + r]      = acc0[r];
        zs[wv][l15][16 + (lane >> 4) * 4 + r] = acc1[r];
    }
    __syncthreads();

    if (tid < 128) {
        float zz[4];
#pragma unroll
        for (int g = 0; g < 4; ++g) {
            float s = pz[g];
#pragma unroll
            for (int u = 0; u < 8; ++u) s += zs[u][g * 4 + rd][rb];
            zz[g] = s;
        }
        float si = 1.f / (1.f + expf(-zz[0]));
        float sf = 1.f / (1.f + expf(-zz[1]));
        float gg = fmaxf(zz[2], 0.f);
        float so = 1.f / (1.f + expf(-zz[3]));
        int hi = rb * HH + blk * 4 + rd;
        float cv = c[hi];
        cv = sf * cv + si * gg;
        c[hi] = cv;
        float hn = so * fmaxf(cv, 0.f);
        h_out[hi] = hn;
        seq_t[hi] = hn;
        unsigned short s1 = rne_bf16(hn);
        float r1 = hn - bf16f(s1);
        unsigned short s2 = rne_bf16(r1);
        float r2 = r1 - bf16f(s2);
        Ho1[hi] = s1; Ho2[hi] = s2; Ho3[hi] = rne_bf16(r2);
    }
}

// ---------- R9 step (fp32 WrT, 512 thr) — fallback ----------
__global__ __launch_bounds__(512) void k_step_T3(const float* __restrict__ WrT, const float* __restrict__ xw_t,
                                                 float* __restrict__ seq_t, const float* __restrict__ h_in,
                                                 float* __restrict__ h_out, float* __restrict__ c) {
    __shared__ float h_lds[34816];
    __shared__ float zred[8][32][17];
    int tid = threadIdx.x;
    int j = tid & 15, ks = tid >> 4;
    int hc0 = blockIdx.x * 4;
    int col = (j >> 2) * HH + hc0 + (j & 3);

    const float4* WrT4 = (const float4*)WrT;
    int wbase = col * 256 + ks * 8;
    float4 w[8];
#pragma unroll
    for (int q = 0; q < 8; ++q) w[q] = WrT4[wbase + q];

    int rb = tid >> 2, rd = tid & 3;
    float pz[4];
    if (tid < 128) {
#pragma unroll
        for (int g = 0; g < 4; ++g) pz[g] = xw_t[rb * GG + g * HH + hc0 + rd];
    }

    const float4* hp4 = (const float4*)h_in;
    float4* hl4w = (float4*)h_lds;
#pragma unroll 8
    for (int it = 0; it < 16; ++it) {
        int gi = it * 512 + tid;
        float4 v = hp4[gi];
        int b = gi >> 8, kk = gi & 255;
        hl4w[b * 272 + (kk >> 4) * 17 + (kk & 15)] = v;
    }
    __syncthreads();

    const float4* hl4 = (const float4*)h_lds;
    int base4 = (ks >> 1) * 17 + (ks & 1) * 8;
    float acc[32];
#pragma unroll
    for (int b = 0; b < 32; ++b) acc[b] = 0.f;
#pragma unroll
    for (int q = 0; q < 8; ++q) {
        float4 wq = w[q];
#pragma unroll
        for (int b = 0; b < 32; ++b) {
            float4 hv = hl4[b * 272 + base4 + q];
            acc[b] += wq.x * hv.x + wq.y * hv.y + wq.z * hv.z + wq.w * hv.w;
        }
    }
#pragma unroll
    for (int b = 0; b < 32; ++b) {
        acc[b] += __shfl_xor(acc[b], 16);
        acc[b] += __shfl_xor(acc[b], 32);
    }
    int wv = tid >> 6;
    if ((ks & 3) == 0) {
#pragma unroll
        for (int b = 0; b < 32; ++b) zred[wv][b][j] = acc[b];
    }
    __syncthreads();

    if (tid < 128) {
        float zz[4];
#pragma unroll
        for (int g = 0; g < 4; ++g) {
            float s = pz[g];
#pragma unroll
            for (int u = 0; u < 8; ++u) s += zred[u][rb][g * 4 + rd];
            zz[g] = s;
        }
        float si = 1.f / (1.f + expf(-zz[0]));
        float sf = 1.f / (1.f + expf(-zz[1]));
        float gg = fmaxf(zz[2], 0.f);
        float so = 1.f / (1.f + expf(-zz[3]));
        float cv = c[rb * HH + hc0 + rd];
        cv = sf * cv + si * gg;
        c[rb * HH + hc0 + rd] = cv;
        float hn = so * fmaxf(cv, 0.f);
        h_out[rb * HH + hc0 + rd] = hn;
        seq_t[rb * HH + hc0 + rd] = hn;
    }
}

// ---------- R2 fallback step (row-major Wr, 256 thr) ----------
__global__ __launch_bounds__(256) void k_step(const float* __restrict__ Wr, const float* __restrict__ xw_t,
                                              float* __restrict__ seq_t, const float* __restrict__ h_in,
                                              float* __restrict__ h_out, float* __restrict__ c) {
    __shared__ float zred[4][32][17];
    int tid = threadIdx.x;
    int j = tid & 15, ks = tid >> 4;
    int hc0 = blockIdx.x * 4;
    int col = (j >> 2) * HH + hc0 + (j & 3);
    float4 w[16];
#pragma unroll
    for (int q = 0; q < 16; ++q) {
        size_t kb = (size_t)(ks * 64 + q * 4) * GG + col;
        w[q].x = Wr[kb];
        w[q].y = Wr[kb + GG];
        w[q].z = Wr[kb + 2 * (size_t)GG];
        w[q].w = Wr[kb + 3 * (size_t)GG];
    }
    const float4* hp = (const float4*)h_in;
    int kq0 = ks * 16;
    float acc[32];
#pragma unroll
    for (int b = 0; b < 32; ++b) acc[b] = 0.f;
#pragma unroll
    for (int q = 0; q < 16; ++q) {
        float4 wq = w[q];
#pragma unroll
        for (int b = 0; b < 32; ++b) {
            float4 hv = hp[b * 256 + kq0 + q];
            acc[b] += wq.x * hv.x + wq.y * hv.y + wq.z * hv.z + wq.w * hv.w;
        }
    }
#pragma unroll
    for (int b = 0; b < 32; ++b) {
        acc[b] += __shfl_xor(acc[b], 16);
        acc[b] += __shfl_xor(acc[b], 32);
    }
    int wv = tid >> 6;
    if ((ks & 3) == 0) {
#pragma unroll
        for (int b = 0; b < 32; ++b) zred[wv][b][j] = acc[b];
    }
    __syncthreads();
    if (tid < 128) {
        int rb = tid >> 2, rd = tid & 3;
        float zz[4];
#pragma unroll
        for (int g = 0; g < 4; ++g) {
            float s = xw_t[rb * GG + g * HH + hc0 + rd];
#pragma unroll
            for (int u = 0; u < 4; ++u) s += zred[u][rb][g * 4 + rd];
            zz[g] = s;
        }
        float si = 1.f / (1.f + expf(-zz[0]));
        float sf = 1.f / (1.f + expf(-zz[1]));
        float gg = fmaxf(zz[2], 0.f);
        float so = 1.f / (1.f + expf(-zz[3]));
        float cv = c[rb * HH + hc0 + rd];
        cv = sf * cv + si * gg;
        c[rb * HH + hc0 + rd] = cv;
        float hn = so * fmaxf(cv, 0.f);
        h_out[rb * HH + hc0 + rd] = hn;
        seq_t[rb * HH + hc0 + rd] = hn;
    }
}

extern "C" void kernel_launch(void* const* d_in, const int* in_sizes, int n_in,
                              void* d_out, int out_size, void* d_ws, size_t ws_size,
                              hipStream_t stream) {
    const float* x  = (const float*)d_in[0];
    const float* h0 = (const float*)d_in[1];
    const float* c0 = (const float*)d_in[2];
    const float* Wk = (const float*)d_in[3];
    const float* Wr = (const float*)d_in[4];
    const float* bs = (const float*)d_in[5];
    const float* Wd = (const float*)d_in[6];
    const float* bd = (const float*)d_in[7];
    float* out = (float*)d_out;
    float* ws  = (float*)d_ws;

    float* xw  = ws;                         // [T][B][4H]  (128 MB)
    float* seq = ws + 33554432;              // [T][B][H]   (32 MB)
    float* h0b = seq + 8388608;              // fp32 h ping A
    float* h1b = h0b + 32768;                // fp32 h ping B
    float* c   = h1b + 32768;
    float* wrt = c + 32768;                  // fp32 WrT (fallback)
    const size_t base_floats = 46235648;
    unsigned short* wkt1 = (unsigned short*)(ws + base_floats);
    unsigned short* wkt2 = wkt1 + 4194304;
    unsigned short* wkt3 = wkt2 + 4194304;
    unsigned short* wrb1 = wkt3 + 4194304;   // gate-permuted bf16x3 Wr
    unsigned short* wrb2 = wrb1 + 4194304;
    unsigned short* wrb3 = wrb2 + 4194304;
    unsigned short* hA1  = wrb3 + 4194304;   // h bf16x3 ping A
    unsigned short* hA2  = hA1 + 32768;
    unsigned short* hA3  = hA2 + 32768;
    unsigned short* hB1  = hA3 + 32768;      // h bf16x3 ping B
    unsigned short* hB2  = hB1 + 32768;
    unsigned short* hB3  = hB2 + 32768;

    bool fast     = ws_size >= base_floats * 4;
    bool mfma_ok  = ws_size >= base_floats * 4 + (size_t)3 * 4194304 * 2;
    bool mfma2_ok = ws_size >= base_floats * 4 + (size_t)6 * 4194304 * 2 + 6 * 32768 * 2;

    k_transpose<<<8192, 256, 0, stream>>>(x, seq);
    if (mfma2_ok)
        k_init_hc2<<<32, 256, 0, stream>>>(h0, c0, h0b, c, hA1, hA2, hA3);
    else
        k_init_hc<<<32, 256, 0, stream>>>(h0, c0, h0b, c);

    for (int l = 0; l < 4; ++l) {
        const float* Wrl = Wr + (size_t)l * 1024 * 4096;
        const float* Wkl = Wk + (size_t)l * 1024 * 4096;
        if (mfma_ok) {
            k_wkt3<<<dim3(64, 16), 256, 0, stream>>>(Wkl, wkt1, wkt2, wkt3);
            k_gemm_mx3<<<dim3(64, 32), 256, 0, stream>>>(seq, wkt1, wkt2, wkt3, bs + l * 4096, xw);
        } else {
            k_gemm<0><<<dim3(64, 32), 256, 0, stream>>>(seq, Wkl, bs + l * 4096, xw, 4096);
        }
        if (mfma2_ok) {
            k_wrt3<<<dim3(64, 16), 256, 0, stream>>>(Wrl, wrb1, wrb2, wrb3);
            for (int t = 0; t < TT; ++t) {
                float* hout = (t & 1) ? h0b : h1b;
                const unsigned short* i1 = (t & 1) ? hB1 : hA1;
                const unsigned short* i2 = (t & 1) ? hB2 : hA2;
                const unsigned short* i3 = (t & 1) ? hB3 : hA3;
                unsigned short* o1 = (t & 1) ? hA1 : hB1;
                unsigned short* o2 = (t & 1) ? hA2 : hB2;
                unsigned short* o3 = (t & 1) ? hA3 : hB3;
                k_step_mfma<<<256, 512, 0, stream>>>(wrb1, wrb2, wrb3, i1, i2, i3, o1, o2, o3,
                                                     xw + (size_t)t * (BB * GG),
                                                     seq + (size_t)t * (BB * HH), hout, c);
            }
        } else {
            if (fast) k_wrt<<<dim3(64, 16), 256, 0, stream>>>(Wrl, wrt);
            for (int t = 0; t < TT; ++t) {
                const float* hin = (t & 1) ? h1b : h0b;
                float* hout      = (t & 1) ? h0b : h1b;
                if (fast)
                    k_step_T3<<<256, 512, 0, stream>>>(wrt, xw + (size_t)t * (BB * GG),
                                                       seq + (size_t)t * (BB * HH), hin, hout, c);
                else
                    k_step<<<256, 256, 0, stream>>>(Wrl, xw + (size_t)t * (BB * GG),
                                                    seq + (size_t)t * (BB * HH), hin, hout, c);
            }
        }
    }

    k_gemm<1><<<dim3(64, 8), 256, 0, stream>>>(seq, Wd, bd, out, 1024);
    k_copy_hc<<<32, 256, 0, stream>>>(h0b, c, out + 8388608, out + 8388608 + 32768);
}